// Round 13
// baseline (143.883 us; speedup 1.0000x reference)
//
#include <hip/hip_runtime.h>
#include <cstdint>
#include <cstddef>

#define SEQ   2048
#define HID   2048
#define NHEAD 16
#define HDIM  128
#define NQKV  2560
#define KOFF  2048
#define VOFF  2304
#define SCALE 0.08838834764831845f

typedef __bf16 bf16_t;
typedef __attribute__((ext_vector_type(8))) __bf16 bf16x8;
typedef __attribute__((ext_vector_type(4))) float f32x4;

static __device__ __forceinline__ void gl_lds16(const void* g, void* l) {
  __builtin_amdgcn_global_load_lds((const __attribute__((address_space(1))) void*)g,
                                   (__attribute__((address_space(3))) void*)l, 16, 0, 0);
}

// ---------- fused prep: x->bf16, Wq/Wk/Wv transposes (vectorized), bias ----------
// blocks: [0,2048) cvt ; [2048,3072) Wq ; [3072,3200) Wk ; [3200,3328) Wv ;
// [3328,3338) bias.  (Wo transpose lives in k_proj's grid.)
__global__ __launch_bounds__(256) void k_prep(const float* __restrict__ x,
                                              const float* __restrict__ Wq,
                                              const float* __restrict__ Wk,
                                              const float* __restrict__ Wv,
                                              const float* __restrict__ bq,
                                              const float* __restrict__ bk,
                                              const float* __restrict__ bv,
                                              bf16_t* __restrict__ xb,
                                              bf16_t* __restrict__ WqkvT,
                                              float* __restrict__ bias) {
  __shared__ float t[64][68];
  int b = blockIdx.x;
  const int tid = threadIdx.x;
  if (b < 2048) {  // x convert, 8 floats/thread
    int i = b * 256 + tid;
    const float4* p = (const float4*)x;
    float4 a = p[2 * i], c = p[2 * i + 1];
    bf16x8 o;
    o[0] = (bf16_t)a.x; o[1] = (bf16_t)a.y; o[2] = (bf16_t)a.z; o[3] = (bf16_t)a.w;
    o[4] = (bf16_t)c.x; o[5] = (bf16_t)c.y; o[6] = (bf16_t)c.z; o[7] = (bf16_t)c.w;
    ((bf16x8*)xb)[i] = o;
    return;
  }
  b -= 2048;
  const float* src;
  bf16_t* dst;
  int N, bx, by;
  if (b < 1024) {
    src = Wq; dst = WqkvT; N = 2048; bx = b & 31; by = b >> 5;
  } else if (b < 1152) {
    int tb = b - 1024; src = Wk; dst = WqkvT + (size_t)2048 * 2048; N = 256; bx = tb & 3; by = tb >> 2;
  } else if (b < 1280) {
    int tb = b - 1152; src = Wv; dst = WqkvT + (size_t)2304 * 2048; N = 256; bx = tb & 3; by = tb >> 2;
  } else {
    int i = (b - 1280) * 256 + tid;
    if (i < NQKV) bias[i] = (i < KOFF) ? bq[i] : ((i < VOFF) ? bk[i - KOFF] : bv[i - VOFF]);
    return;
  }
  const int c0 = bx * 64, r0 = by * 64;
  const int f4c = tid & 15, rw = tid >> 4;
#pragma unroll
  for (int j = 0; j < 4; ++j) {
    int r = j * 16 + rw;
    float4 v = *(const float4*)&src[(size_t)(r0 + r) * N + c0 + f4c * 4];
    *(float4*)&t[r][f4c * 4] = v;
  }
  __syncthreads();
  const int c = tid >> 2, q = tid & 3;
  bf16x8 o0, o1;
#pragma unroll
  for (int i = 0; i < 8; ++i) {
    o0[i] = (bf16_t)t[q * 16 + i][c];
    o1[i] = (bf16_t)t[q * 16 + 8 + i][c];
  }
  bf16_t* dp = dst + (size_t)(c0 + c) * 2048 + r0 + q * 16;
  *(bf16x8*)dp = o0;
  *(bf16x8*)(dp + 8) = o1;
}

// ---------- fused projection GEMM + Wo transpose (grid = 1664) ----------
// bid<576  : QK  : C[0:2048,0:2304) = xb @ WqkvT^T + bias (BM=128,BN=64,BK=32)
// 576..640 : V^T : Vg[d][sigma(s)] = WvT @ xb^T + bv      (BM=128,BN=64,BK=32)
// bid>=640 : Wo transpose (consumed only by the O-GEMM, two kernels later).
// QK retiled to the ogemm-proven 128x64 / 2+ blocks-per-CU regime.
__global__ __launch_bounds__(256) void k_proj(const bf16_t* __restrict__ xb,
                                              const bf16_t* __restrict__ WqkvT,
                                              const float* __restrict__ bias,
                                              const float* __restrict__ Wo,
                                              bf16_t* __restrict__ WoT,
                                              bf16_t* __restrict__ QKV,
                                              bf16_t* __restrict__ Vg) {
  __shared__ __align__(16) char smem[36864];
  const int tid = threadIdx.x;
  const int l = tid & 63, w = tid >> 6;
  const int lr = l & 15, lg = l >> 4;
  const int bid = blockIdx.x;
  const int K = 2048, NT = 64;

  if (bid >= 640) {  // ---- Wo transpose (vectorized 64x64 tile) ----
    float (*t)[68] = (float(*)[68])smem;
    const int b3 = bid - 640;
    const int bx = b3 & 31, by = b3 >> 5;
    const int c0 = bx * 64, r0 = by * 64;
    const int f4c = tid & 15, rw = tid >> 4;
#pragma unroll
    for (int j = 0; j < 4; ++j) {
      int r = j * 16 + rw;
      float4 v = *(const float4*)&Wo[(size_t)(r0 + r) * 2048 + c0 + f4c * 4];
      *(float4*)&t[r][f4c * 4] = v;
    }
    __syncthreads();
    const int c = tid >> 2, q = tid & 3;
    bf16x8 o0, o1;
#pragma unroll
    for (int i = 0; i < 8; ++i) {
      o0[i] = (bf16_t)t[q * 16 + i][c];
      o1[i] = (bf16_t)t[q * 16 + 8 + i][c];
    }
    bf16_t* dp = WoT + (size_t)(c0 + c) * 2048 + r0 + q * 16;
    *(bf16x8*)dp = o0;
    *(bf16x8*)(dp + 8) = o1;
    return;
  }

  // ---- GEMM paths: BM=128, BN=64, BK=32; A 2 chunks + B 1 chunk per stage ----
  bf16_t* As = (bf16_t*)smem;            // [3][128*32] = 24KB
  bf16_t* Bs = (bf16_t*)(smem + 24576);  // [3][64*32]  = 12KB
  const bf16_t* Ap;
  const bf16_t* Bp;
  int m0, n0;
  bool isQK = (bid < 576);
  if (isQK) {
    const int b = (bid & 7) * 72 + (bid >> 3);  // XCD swizzle (576 = 8*72)
    m0 = (b / 36) * 128; n0 = (b % 36) * 64;
    Ap = xb; Bp = WqkvT;
  } else {
    const int b2 = bid - 576;
    m0 = (b2 >> 5) * 128; n0 = (b2 & 31) * 64;
    Ap = WqkvT + (size_t)VOFF * 2048;  // WvT rows = d
    Bp = xb;                            // cols = s
  }
  const int wm = (w >> 1) * 64, wn = (w & 1) * 32;
  f32x4 acc[4][2] = {};

#define PSTAGE(buf, ktv)                                                         \
  {                                                                              \
    _Pragma("unroll") for (int t = 0; t < 2; ++t) {                              \
      int c = t * 256 + tid;                                                     \
      int r = c >> 2, ss = (c & 3) ^ ((r >> 1) & 3);                             \
      gl_lds16(Ap + (size_t)(m0 + r) * K + (ktv) + ss * 8,                       \
               As + (size_t)(buf) * 4096 + (size_t)(t * 256 + w * 64) * 8);      \
    }                                                                            \
    {                                                                            \
      int c = tid;                                                               \
      int r = c >> 2, ss = (c & 3) ^ ((r >> 1) & 3);                             \
      gl_lds16(Bp + (size_t)(n0 + r) * K + (ktv) + ss * 8,                       \
               Bs + (size_t)(buf) * 2048 + (size_t)(w * 64) * 8);                \
    }                                                                            \
  }
  PSTAGE(0, 0);
  PSTAGE(1, 32);
  int bufc = 0;
  for (int i = 0; i < NT; ++i) {
    if (i + 2 < NT) {
      int bn = bufc + 2; if (bn >= 3) bn -= 3;
      PSTAGE(bn, (i + 2) * 32);
      asm volatile("s_waitcnt vmcnt(6)" ::: "memory");
    } else if (i + 2 == NT) {
      asm volatile("s_waitcnt vmcnt(3)" ::: "memory");
    } else {
      asm volatile("s_waitcnt vmcnt(0)" ::: "memory");
    }
    asm volatile("s_barrier" ::: "memory");
    bf16x8 af[4], bfr[2];
#pragma unroll
    for (int i4 = 0; i4 < 4; ++i4) {
      int ra = wm + i4 * 16 + lr;
      af[i4] = *(const bf16x8*)(As + (size_t)bufc * 4096 + ra * 32 + ((lg ^ ((ra >> 1) & 3)) * 8));
    }
#pragma unroll
    for (int i4 = 0; i4 < 2; ++i4) {
      int rb = wn + i4 * 16 + lr;
      bfr[i4] = *(const bf16x8*)(Bs + (size_t)bufc * 2048 + rb * 32 + ((lg ^ ((rb >> 1) & 3)) * 8));
    }
#pragma unroll
    for (int mi = 0; mi < 4; ++mi)
#pragma unroll
      for (int ni = 0; ni < 2; ++ni)
        acc[mi][ni] =
            __builtin_amdgcn_mfma_f32_16x16x32_bf16(af[mi], bfr[ni], acc[mi][ni], 0, 0, 0);
    asm volatile("s_barrier" ::: "memory");
    bufc = (bufc + 1 == 3) ? 0 : bufc + 1;
  }
#undef PSTAGE

  if (isQK) {
#pragma unroll
    for (int mi = 0; mi < 4; ++mi)
#pragma unroll
      for (int ni = 0; ni < 2; ++ni) {
        int col = n0 + wn + ni * 16 + lr;
        float bb = bias[col];
#pragma unroll
        for (int r = 0; r < 4; ++r) {
          int row = m0 + wm + mi * 16 + lg * 4 + r;
          QKV[(size_t)row * NQKV + col] = (bf16_t)(acc[mi][ni][r] + bb);
        }
      }
  } else {
#pragma unroll
    for (int mi = 0; mi < 4; ++mi)
#pragma unroll
      for (int ni = 0; ni < 2; ++ni) {
        int s = n0 + wn + ni * 16 + lr;
        int sig = (s & ~31) | ((s & 15) << 1) | ((s >> 4) & 1);
#pragma unroll
        for (int r = 0; r < 4; ++r) {
          int d = m0 + wm + mi * 16 + lg * 4 + r;
          Vg[(size_t)d * SEQ + sig] = (bf16_t)(acc[mi][ni][r] + bias[VOFF + d]);
        }
      }
  }
}

// ---------- O-projection GEMM: 128x64 tiles, grid 512 = 2 blocks/CU ----------
__global__ __launch_bounds__(256) void k_ogemm(const bf16_t* __restrict__ A,
                                               const bf16_t* __restrict__ Bt,
                                               float* __restrict__ C) {
  __shared__ __align__(16) bf16_t As[3][128 * 32];
  __shared__ __align__(16) bf16_t Bs[3][64 * 32];
  const int tid = threadIdx.x;
  const int l = tid & 63, w = tid >> 6;
  const int lr = l & 15, lg = l >> 4;
  const int bid = blockIdx.x;
  const int swz = (bid & 7) * 64 + (bid >> 3);  // 512 = 8*64
  const int m0 = (swz >> 5) * 128, n0 = (swz & 31) * 64;
  const int wm = (w >> 1) * 64, wn = (w & 1) * 32;
  const int K = 2048, NT = 64;
  f32x4 acc[4][2] = {};

#define OSTAGE(buf, ktv)                                                         \
  {                                                                              \
    _Pragma("unroll") for (int t = 0; t < 2; ++t) {                              \
      int c = t * 256 + tid;                                                     \
      int r = c >> 2, ss = (c & 3) ^ ((r >> 1) & 3);                             \
      gl_lds16(A + (size_t)(m0 + r) * K + (ktv) + ss * 8,                        \
               &As[buf][(size_t)(t * 256 + w * 64) * 8]);                        \
    }                                                                            \
    {                                                                            \
      int c = tid;                                                               \
      int r = c >> 2, ss = (c & 3) ^ ((r >> 1) & 3);                             \
      gl_lds16(Bt + (size_t)(n0 + r) * K + (ktv) + ss * 8,                       \
               &Bs[buf][(size_t)(w * 64) * 8]);                                  \
    }                                                                            \
  }

  OSTAGE(0, 0);
  OSTAGE(1, 32);
  int bufc = 0;
  for (int i = 0; i < NT; ++i) {
    if (i + 2 < NT) {
      int bn = bufc + 2; if (bn >= 3) bn -= 3;
      OSTAGE(bn, (i + 2) * 32);
      asm volatile("s_waitcnt vmcnt(6)" ::: "memory");
    } else if (i + 2 == NT) {
      asm volatile("s_waitcnt vmcnt(3)" ::: "memory");
    } else {
      asm volatile("s_waitcnt vmcnt(0)" ::: "memory");
    }
    asm volatile("s_barrier" ::: "memory");
    bf16x8 af[4], bfr[2];
#pragma unroll
    for (int i4 = 0; i4 < 4; ++i4) {
      int ra = wm + i4 * 16 + lr;
      af[i4] = *(const bf16x8*)&As[bufc][ra * 32 + ((lg ^ ((ra >> 1) & 3)) * 8)];
    }
#pragma unroll
    for (int i4 = 0; i4 < 2; ++i4) {
      int rb = wn + i4 * 16 + lr;
      bfr[i4] = *(const bf16x8*)&Bs[bufc][rb * 32 + ((lg ^ ((rb >> 1) & 3)) * 8)];
    }
#pragma unroll
    for (int mi = 0; mi < 4; ++mi)
#pragma unroll
      for (int ni = 0; ni < 2; ++ni)
        acc[mi][ni] =
            __builtin_amdgcn_mfma_f32_16x16x32_bf16(af[mi], bfr[ni], acc[mi][ni], 0, 0, 0);
    asm volatile("s_barrier" ::: "memory");
    bufc = (bufc + 1 == 3) ? 0 : bufc + 1;
  }
#undef OSTAGE

#pragma unroll
  for (int mi = 0; mi < 4; ++mi)
#pragma unroll
    for (int ni = 0; ni < 2; ++ni) {
      int col = n0 + wn + ni * 16 + lr;
#pragma unroll
      for (int r = 0; r < 4; ++r) {
        int row = m0 + wm + mi * 16 + lg * 4 + r;
        C[(size_t)row * 2048 + col] = acc[mi][ni][r];
      }
    }
}

// ---------- flash attention — R12 kernel + V-fragment hoist ----------
// grid (16 heads, 32 qblocks); block 256 = 4 waves, each wave 16 q rows. KVBLK=64.
// Counted-vmcnt dbuf schedule; swapped QK^T; in-register P; defer-max THR=8.
// NEW: all 16 V ds_read_b128 hoisted before the softmax (independent of QK^T
// results) so their latency hides under the softmax VALU chain.
__global__ __launch_bounds__(256) void k_attn(const bf16_t* __restrict__ QKV,
                                              const bf16_t* __restrict__ Vg,
                                              bf16_t* __restrict__ AO) {
  __shared__ __align__(16) bf16_t Kl[2 * 64 * 128];
  __shared__ __align__(16) bf16_t Vl[2 * 64 * 128];
  const int h = blockIdx.x;
  const int y = blockIdx.y;
  const int qb = (y < 16) ? (31 - y) : (y - 16);  // pair heavy+light per CU (sum=33)
  const int hkv = h >> 3;
  const int tid = threadIdx.x;
  const int l = tid & 63, w = tid >> 6;
  const int lr = l & 15, lg = l >> 4;
  const int q0 = qb * 64 + w * 16;

  // Q fragments (B-operand: col=lane&15 -> q=lr ; dh-slot=(lane>>4)*8+e)
  bf16x8 qf[4];
#pragma unroll
  for (int dt = 0; dt < 4; ++dt)
    qf[dt] = *(const bf16x8*)(QKV + (size_t)(q0 + lr) * NQKV + h * HDIM + dt * 32 + lg * 8);

  f32x4 oa[8] = {};
  float m = -1e30f, ls = 0.0f;

  // staging source pointers (pre-swizzled global source, linear LDS dest)
  const bf16_t* srcK[4];
  const bf16_t* srcV[4];
#pragma unroll
  for (int t = 0; t < 4; ++t) {
    int c = t * 256 + tid;
    int r = c >> 4, ss = (c & 15) ^ (r & 15);
    srcK[t] = QKV + (size_t)r * NQKV + KOFF + hkv * HDIM + ss * 8;
    srcV[t] = Vg + (size_t)(hkv * HDIM + 2 * r + (ss >> 3)) * SEQ + (ss & 7) * 8;
  }

#define STAGE(b, kbv)                                                        \
  {                                                                          \
    bf16_t* Kb = Kl + (b) * 8192;                                            \
    bf16_t* Vb = Vl + (b) * 8192;                                            \
    _Pragma("unroll") for (int t = 0; t < 4; ++t)                            \
        gl_lds16(srcK[t] + (size_t)(kbv) * 64 * NQKV,                        \
                 Kb + (size_t)(t * 256 + w * 64) * 8);                       \
    _Pragma("unroll") for (int t = 0; t < 4; ++t)                            \
        gl_lds16(srcV[t] + (kbv) * 64, Vb + (size_t)(t * 256 + w * 64) * 8); \
  }

  // prologue: stage tiles 0 and 1 (tile 1 junk when qb==0 — in-bounds, unused)
  STAGE(0, 0);
  STAGE(1, 1);
  asm volatile("s_waitcnt vmcnt(8)" ::: "memory");
  asm volatile("s_barrier" ::: "memory");

  for (int kb = 0; kb <= qb; ++kb) {
    const bf16_t* Kb = Kl + (kb & 1) * 8192;
    const bf16_t* Vb = Vl + (kb & 1) * 8192;

    // S^T = K @ Q^T : lane holds S[k=ki*16+lg*4+r][q=lr]
    float sc[4][4];
#pragma unroll
    for (int ki = 0; ki < 4; ++ki) {
      f32x4 sa = {};
      int krow = ki * 16 + lr;
#pragma unroll
      for (int dt = 0; dt < 4; ++dt) {
        bf16x8 kf = *(const bf16x8*)(Kb + krow * 128 + (((dt * 4 + lg) ^ lr) * 8));
        sa = __builtin_amdgcn_mfma_f32_16x16x32_bf16(kf, qf[dt], sa, 0, 0, 0);
      }
#pragma unroll
      for (int r = 0; r < 4; ++r) {
        float s = sa[r] * SCALE;
        if (kb == qb) {
          int kg = kb * 64 + ki * 16 + lg * 4 + r;
          if (kg > q0 + lr) s = -1e30f;
        }
        sc[ki][r] = s;
      }
    }

    // V fragments hoisted: independent of QK^T results; ds_read latency hides
    // under the softmax VALU chain below.
    bf16x8 vf[2][8];
#pragma unroll
    for (int kp = 0; kp < 2; ++kp)
#pragma unroll
      for (int dt = 0; dt < 8; ++dt) {
        int R = dt * 8 + (lr >> 1);
        int slot = (((lr & 1) * 8 + kp * 4 + lg) ^ (R & 15));
        vf[kp][dt] = *(const bf16x8*)(Vb + R * 128 + slot * 8);
      }

    // online softmax for q=lr: in-lane tree over 16 + 2 shfl across lg groups
    float t0 = fmaxf(fmaxf(sc[0][0], sc[0][1]), fmaxf(sc[0][2], sc[0][3]));
    float t1 = fmaxf(fmaxf(sc[1][0], sc[1][1]), fmaxf(sc[1][2], sc[1][3]));
    float t2 = fmaxf(fmaxf(sc[2][0], sc[2][1]), fmaxf(sc[2][2], sc[2][3]));
    float t3 = fmaxf(fmaxf(sc[3][0], sc[3][1]), fmaxf(sc[3][2], sc[3][3]));
    float tm = fmaxf(fmaxf(t0, t1), fmaxf(t2, t3));
    tm = fmaxf(tm, __shfl_xor(tm, 16));
    tm = fmaxf(tm, __shfl_xor(tm, 32));

    // T13 defer-max: only rescale when some q-row's max grew beyond m+8.
    if (!__all(tm <= m + 8.0f)) {
      float mn = fmaxf(m, tm);
      float al = __expf(m - mn);
      m = mn;
      ls *= al;
      float a0 = __shfl(al, lg * 4 + 0);
      float a1 = __shfl(al, lg * 4 + 1);
      float a2 = __shfl(al, lg * 4 + 2);
      float a3 = __shfl(al, lg * 4 + 3);
#pragma unroll
      for (int dt = 0; dt < 8; ++dt) {
        oa[dt][0] *= a0; oa[dt][1] *= a1; oa[dt][2] *= a2; oa[dt][3] *= a3;
      }
    }

    float rs = 0.0f;
#pragma unroll
    for (int ki = 0; ki < 4; ++ki) {
      float p0 = __expf(sc[ki][0] - m), p1 = __expf(sc[ki][1] - m);
      float p2 = __expf(sc[ki][2] - m), p3 = __expf(sc[ki][3] - m);
      sc[ki][0] = p0; sc[ki][1] = p1; sc[ki][2] = p2; sc[ki][3] = p3;
      rs += (p0 + p1) + (p2 + p3);
    }
    rs += __shfl_xor(rs, 16);
    rs += __shfl_xor(rs, 32);
    ls += rs;

    // pack P into A-fragments: pf[kp][e] = sc[2kp+(e&1)][e>>1]
    bf16x8 pf[2];
#pragma unroll
    for (int kp = 0; kp < 2; ++kp) {
      pf[kp][0] = (bf16_t)sc[2 * kp][0]; pf[kp][1] = (bf16_t)sc[2 * kp + 1][0];
      pf[kp][2] = (bf16_t)sc[2 * kp][1]; pf[kp][3] = (bf16_t)sc[2 * kp + 1][1];
      pf[kp][4] = (bf16_t)sc[2 * kp][2]; pf[kp][5] = (bf16_t)sc[2 * kp + 1][2];
      pf[kp][6] = (bf16_t)sc[2 * kp][3]; pf[kp][7] = (bf16_t)sc[2 * kp + 1][3];
    }

    // O += P @ V  (C[q][d]: col=lane&15=d, row=lg*4+reg=q)
#pragma unroll
    for (int kp = 0; kp < 2; ++kp)
#pragma unroll
      for (int dt = 0; dt < 8; ++dt)
        oa[dt] = __builtin_amdgcn_mfma_f32_16x16x32_bf16(pf[kp], vf[kp][dt], oa[dt], 0, 0, 0);

    // pipeline turn: free buf[kb&1], refill with tile kb+2, wait tile kb+1
    asm volatile("s_barrier" ::: "memory");
    if (kb + 2 <= qb) {
      STAGE(kb & 1, kb + 2);
      asm volatile("s_waitcnt vmcnt(8)" ::: "memory");
      asm volatile("s_barrier" ::: "memory");
    } else if (kb + 1 <= qb) {
      asm volatile("s_waitcnt vmcnt(0)" ::: "memory");
      asm volatile("s_barrier" ::: "memory");
    }
  }
#undef STAGE
  asm volatile("s_waitcnt vmcnt(0)" ::: "memory");

  // epilogue: normalize and store; lane holds O[q=lg*4+r][d=dt*16+lr]
  float l0 = __shfl(ls, lg * 4 + 0);
  float l1 = __shfl(ls, lg * 4 + 1);
  float l2 = __shfl(ls, lg * 4 + 2);
  float l3 = __shfl(ls, lg * 4 + 3);
  float i0 = 1.0f / l0, i1 = 1.0f / l1, i2 = 1.0f / l2, i3 = 1.0f / l3;
#pragma unroll
  for (int dt = 0; dt < 8; ++dt) {
    int d = h * HDIM + dt * 16 + lr;
    AO[(size_t)(q0 + lg * 4 + 0) * HID + d] = (bf16_t)(oa[dt][0] * i0);
    AO[(size_t)(q0 + lg * 4 + 1) * HID + d] = (bf16_t)(oa[dt][1] * i1);
    AO[(size_t)(q0 + lg * 4 + 2) * HID + d] = (bf16_t)(oa[dt][2] * i2);
    AO[(size_t)(q0 + lg * 4 + 3) * HID + d] = (bf16_t)(oa[dt][3] * i3);
  }
}

extern "C" void kernel_launch(void* const* d_in, const int* in_sizes, int n_in,
                              void* d_out, int out_size, void* d_ws, size_t ws_size,
                              hipStream_t stream) {
  (void)in_sizes; (void)n_in; (void)out_size; (void)ws_size;
  const float* x  = (const float*)d_in[0];
  const float* Wq = (const float*)d_in[1];
  const float* bq = (const float*)d_in[2];
  const float* Wk = (const float*)d_in[3];
  const float* bk = (const float*)d_in[4];
  const float* Wv = (const float*)d_in[5];
  const float* bv = (const float*)d_in[6];
  const float* Wo = (const float*)d_in[7];
  float* outp = (float*)d_out;

  char* ws = (char*)d_ws;
  const size_t OFF_XB   = 0;                      // [2048][2048] bf16
  const size_t OFF_WQKV = 8388608;                // [2560][2048] bf16 (Wq^T;Wk^T;Wv^T)
  const size_t OFF_WOT  = OFF_WQKV + 10485760;    // [2048][2048] bf16
  const size_t OFF_QKV  = OFF_WOT + 8388608;      // [2048][2560] bf16 (V cols unused)
  const size_t OFF_VT   = OFF_QKV + 10485760;     // [256][2048] bf16 (sigma-interleaved)
  const size_t OFF_AO   = OFF_VT + 1048576;       // [2048][2048] bf16
  const size_t OFF_BIAS = OFF_AO + 8388608;       // [2560] fp32
  bf16_t* xb    = (bf16_t*)(ws + OFF_XB);
  bf16_t* WqkvT = (bf16_t*)(ws + OFF_WQKV);
  bf16_t* WoT   = (bf16_t*)(ws + OFF_WOT);
  bf16_t* QKV   = (bf16_t*)(ws + OFF_QKV);
  bf16_t* Vg    = (bf16_t*)(ws + OFF_VT);
  bf16_t* AO    = (bf16_t*)(ws + OFF_AO);
  float*  bias  = (float*)(ws + OFF_BIAS);

  k_prep<<<3338, 256, 0, stream>>>(x, Wq, Wk, Wv, bq, bk, bv, xb, WqkvT, bias);
  k_proj<<<1664, 256, 0, stream>>>(xb, WqkvT, bias, Wo, WoT, QKV, Vg);
  k_attn<<<dim3(16, 32), 256, 0, stream>>>(QKV, Vg, AO);
  k_ogemm<<<512, 256, 0, stream>>>(AO, WoT, outp);
}

// Round 14
// 132.112 us; speedup vs baseline: 1.0891x; 1.0891x over previous
//
#include <hip/hip_runtime.h>
#include <cstdint>
#include <cstddef>

#define SEQ   2048
#define HID   2048
#define NHEAD 16
#define HDIM  128
#define NQKV  2560
#define KOFF  2048
#define VOFF  2304
#define SCALE 0.08838834764831845f

typedef __bf16 bf16_t;
typedef __attribute__((ext_vector_type(8))) __bf16 bf16x8;
typedef __attribute__((ext_vector_type(4))) float f32x4;

static __device__ __forceinline__ void gl_lds16(const void* g, void* l) {
  __builtin_amdgcn_global_load_lds((const __attribute__((address_space(1))) void*)g,
                                   (__attribute__((address_space(3))) void*)l, 16, 0, 0);
}

// ---------- fused prep: x->bf16, Wq/Wk/Wv transposes (vectorized), bias ----------
// blocks: [0,2048) cvt ; [2048,3072) Wq ; [3072,3200) Wk ; [3200,3328) Wv ;
// [3328,3338) bias.  (Wo transpose lives in k_proj's grid.)
__global__ __launch_bounds__(256) void k_prep(const float* __restrict__ x,
                                              const float* __restrict__ Wq,
                                              const float* __restrict__ Wk,
                                              const float* __restrict__ Wv,
                                              const float* __restrict__ bq,
                                              const float* __restrict__ bk,
                                              const float* __restrict__ bv,
                                              bf16_t* __restrict__ xb,
                                              bf16_t* __restrict__ WqkvT,
                                              float* __restrict__ bias) {
  __shared__ float t[64][68];
  int b = blockIdx.x;
  const int tid = threadIdx.x;
  if (b < 2048) {  // x convert, 8 floats/thread
    int i = b * 256 + tid;
    const float4* p = (const float4*)x;
    float4 a = p[2 * i], c = p[2 * i + 1];
    bf16x8 o;
    o[0] = (bf16_t)a.x; o[1] = (bf16_t)a.y; o[2] = (bf16_t)a.z; o[3] = (bf16_t)a.w;
    o[4] = (bf16_t)c.x; o[5] = (bf16_t)c.y; o[6] = (bf16_t)c.z; o[7] = (bf16_t)c.w;
    ((bf16x8*)xb)[i] = o;
    return;
  }
  b -= 2048;
  const float* src;
  bf16_t* dst;
  int N, bx, by;
  if (b < 1024) {
    src = Wq; dst = WqkvT; N = 2048; bx = b & 31; by = b >> 5;
  } else if (b < 1152) {
    int tb = b - 1024; src = Wk; dst = WqkvT + (size_t)2048 * 2048; N = 256; bx = tb & 3; by = tb >> 2;
  } else if (b < 1280) {
    int tb = b - 1152; src = Wv; dst = WqkvT + (size_t)2304 * 2048; N = 256; bx = tb & 3; by = tb >> 2;
  } else {
    int i = (b - 1280) * 256 + tid;
    if (i < NQKV) bias[i] = (i < KOFF) ? bq[i] : ((i < VOFF) ? bk[i - KOFF] : bv[i - VOFF]);
    return;
  }
  const int c0 = bx * 64, r0 = by * 64;
  const int f4c = tid & 15, rw = tid >> 4;
#pragma unroll
  for (int j = 0; j < 4; ++j) {
    int r = j * 16 + rw;
    float4 v = *(const float4*)&src[(size_t)(r0 + r) * N + c0 + f4c * 4];
    *(float4*)&t[r][f4c * 4] = v;
  }
  __syncthreads();
  const int c = tid >> 2, q = tid & 3;
  bf16x8 o0, o1;
#pragma unroll
  for (int i = 0; i < 8; ++i) {
    o0[i] = (bf16_t)t[q * 16 + i][c];
    o1[i] = (bf16_t)t[q * 16 + 8 + i][c];
  }
  bf16_t* dp = dst + (size_t)(c0 + c) * 2048 + r0 + q * 16;
  *(bf16x8*)dp = o0;
  *(bf16x8*)(dp + 8) = o1;
}

// ---------- fused projection GEMM + Wo transpose (grid = 1376) — R12-proven ----
// bid<288  : QK  : C[0:2048,0:2304) = xb @ WqkvT^T + bias (BM=128,BN=128,BK=32)
// 288..352 : V^T : Vg[d][sigma(s)] = WvT @ xb^T + bv      (BM=128,BN=64, BK=32)
// bid>=352 : Wo transpose (consumed only by the O-GEMM, two kernels later).
// LDS swizzle: ss = sp ^ ((r>>1)&3) -> fragment reads 2-way (free).
__global__ __launch_bounds__(256) void k_proj(const bf16_t* __restrict__ xb,
                                              const bf16_t* __restrict__ WqkvT,
                                              const float* __restrict__ bias,
                                              const float* __restrict__ Wo,
                                              bf16_t* __restrict__ WoT,
                                              bf16_t* __restrict__ QKV,
                                              bf16_t* __restrict__ Vg) {
  __shared__ __align__(16) char smem[61440];
  const int tid = threadIdx.x;
  const int l = tid & 63, w = tid >> 6;
  const int lr = l & 15, lg = l >> 4;
  const int bid = blockIdx.x;
  const int K = 2048, NT = 64;

  if (bid >= 352) {  // ---- Wo transpose (vectorized 64x64 tile) ----
    float (*t)[68] = (float(*)[68])smem;
    const int b3 = bid - 352;
    const int bx = b3 & 31, by = b3 >> 5;
    const int c0 = bx * 64, r0 = by * 64;
    const int f4c = tid & 15, rw = tid >> 4;
#pragma unroll
    for (int j = 0; j < 4; ++j) {
      int r = j * 16 + rw;
      float4 v = *(const float4*)&Wo[(size_t)(r0 + r) * 2048 + c0 + f4c * 4];
      *(float4*)&t[r][f4c * 4] = v;
    }
    __syncthreads();
    const int c = tid >> 2, q = tid & 3;
    bf16x8 o0, o1;
#pragma unroll
    for (int i = 0; i < 8; ++i) {
      o0[i] = (bf16_t)t[q * 16 + i][c];
      o1[i] = (bf16_t)t[q * 16 + 8 + i][c];
    }
    bf16_t* dp = WoT + (size_t)(c0 + c) * 2048 + r0 + q * 16;
    *(bf16x8*)dp = o0;
    *(bf16x8*)(dp + 8) = o1;
    return;
  }

  if (bid < 288) {
    bf16_t* As = (bf16_t*)smem;            // [3][128*32]
    bf16_t* Bs = (bf16_t*)(smem + 24576);  // [3][128*32]
    const int b = (bid & 7) * 36 + (bid >> 3);  // XCD swizzle (288 = 8*36)
    const int m0 = (b / 18) * 128, n0 = (b % 18) * 128;
    const int wm = (w >> 1) * 64, wn = (w & 1) * 64;
    f32x4 acc[4][4] = {};

#define QSTAGE(buf, ktv)                                                         \
  {                                                                              \
    _Pragma("unroll") for (int t = 0; t < 2; ++t) {                              \
      int c = t * 256 + tid;                                                     \
      int r = c >> 2, ss = (c & 3) ^ ((r >> 1) & 3);                             \
      gl_lds16(xb + (size_t)(m0 + r) * K + (ktv) + ss * 8,                       \
               As + (size_t)(buf) * 4096 + (size_t)(t * 256 + w * 64) * 8);      \
    }                                                                            \
    _Pragma("unroll") for (int t = 0; t < 2; ++t) {                              \
      int c = t * 256 + tid;                                                     \
      int r = c >> 2, ss = (c & 3) ^ ((r >> 1) & 3);                             \
      gl_lds16(WqkvT + (size_t)(n0 + r) * K + (ktv) + ss * 8,                    \
               Bs + (size_t)(buf) * 4096 + (size_t)(t * 256 + w * 64) * 8);      \
    }                                                                            \
  }
    QSTAGE(0, 0);
    QSTAGE(1, 32);
    int bufc = 0;
    for (int i = 0; i < NT; ++i) {
      if (i + 2 < NT) {
        int bn = bufc + 2; if (bn >= 3) bn -= 3;
        QSTAGE(bn, (i + 2) * 32);
        asm volatile("s_waitcnt vmcnt(8)" ::: "memory");
      } else if (i + 2 == NT) {
        asm volatile("s_waitcnt vmcnt(4)" ::: "memory");
      } else {
        asm volatile("s_waitcnt vmcnt(0)" ::: "memory");
      }
      asm volatile("s_barrier" ::: "memory");
      bf16x8 af[4], bfr[4];
#pragma unroll
      for (int i4 = 0; i4 < 4; ++i4) {
        int ra = wm + i4 * 16 + lr;
        af[i4] = *(const bf16x8*)(As + (size_t)bufc * 4096 + ra * 32 + ((lg ^ ((ra >> 1) & 3)) * 8));
      }
#pragma unroll
      for (int i4 = 0; i4 < 4; ++i4) {
        int rb = wn + i4 * 16 + lr;
        bfr[i4] = *(const bf16x8*)(Bs + (size_t)bufc * 4096 + rb * 32 + ((lg ^ ((rb >> 1) & 3)) * 8));
      }
#pragma unroll
      for (int mi = 0; mi < 4; ++mi)
#pragma unroll
        for (int ni = 0; ni < 4; ++ni)
          acc[mi][ni] =
              __builtin_amdgcn_mfma_f32_16x16x32_bf16(af[mi], bfr[ni], acc[mi][ni], 0, 0, 0);
      asm volatile("s_barrier" ::: "memory");
      bufc = (bufc + 1 == 3) ? 0 : bufc + 1;
    }
#undef QSTAGE
#pragma unroll
    for (int mi = 0; mi < 4; ++mi)
#pragma unroll
      for (int ni = 0; ni < 4; ++ni) {
        int col = n0 + wn + ni * 16 + lr;
        float bb = bias[col];
#pragma unroll
        for (int r = 0; r < 4; ++r) {
          int row = m0 + wm + mi * 16 + lg * 4 + r;
          QKV[(size_t)row * NQKV + col] = (bf16_t)(acc[mi][ni][r] + bb);
        }
      }
  } else {
    bf16_t* As = (bf16_t*)smem;            // [3][128*32]  (WvT tiles)
    bf16_t* Bs = (bf16_t*)(smem + 24576);  // [3][64*32]   (xb tiles)
    const bf16_t* WvT = WqkvT + (size_t)VOFF * 2048;
    const int b2 = bid - 288;
    const int m0 = (b2 >> 5) * 128, n0 = (b2 & 31) * 64;
    const int wm = (w >> 1) * 64, wn = (w & 1) * 32;
    f32x4 acc[4][2] = {};

#define VSTAGE(buf, ktv)                                                         \
  {                                                                              \
    _Pragma("unroll") for (int t = 0; t < 2; ++t) {                              \
      int c = t * 256 + tid;                                                     \
      int r = c >> 2, ss = (c & 3) ^ ((r >> 1) & 3);                             \
      gl_lds16(WvT + (size_t)(m0 + r) * K + (ktv) + ss * 8,                      \
               As + (size_t)(buf) * 4096 + (size_t)(t * 256 + w * 64) * 8);      \
    }                                                                            \
    {                                                                            \
      int c = tid;                                                               \
      int r = c >> 2, ss = (c & 3) ^ ((r >> 1) & 3);                             \
      gl_lds16(xb + (size_t)(n0 + r) * K + (ktv) + ss * 8,                       \
               Bs + (size_t)(buf) * 2048 + (size_t)(w * 64) * 8);                \
    }                                                                            \
  }
    VSTAGE(0, 0);
    VSTAGE(1, 32);
    int bufc = 0;
    for (int i = 0; i < NT; ++i) {
      if (i + 2 < NT) {
        int bn = bufc + 2; if (bn >= 3) bn -= 3;
        VSTAGE(bn, (i + 2) * 32);
        asm volatile("s_waitcnt vmcnt(6)" ::: "memory");
      } else if (i + 2 == NT) {
        asm volatile("s_waitcnt vmcnt(3)" ::: "memory");
      } else {
        asm volatile("s_waitcnt vmcnt(0)" ::: "memory");
      }
      asm volatile("s_barrier" ::: "memory");
      bf16x8 af[4], bfr[2];
#pragma unroll
      for (int i4 = 0; i4 < 4; ++i4) {
        int ra = wm + i4 * 16 + lr;
        af[i4] = *(const bf16x8*)(As + (size_t)bufc * 4096 + ra * 32 + ((lg ^ ((ra >> 1) & 3)) * 8));
      }
#pragma unroll
      for (int i4 = 0; i4 < 2; ++i4) {
        int rb = wn + i4 * 16 + lr;
        bfr[i4] = *(const bf16x8*)(Bs + (size_t)bufc * 2048 + rb * 32 + ((lg ^ ((rb >> 1) & 3)) * 8));
      }
#pragma unroll
      for (int mi = 0; mi < 4; ++mi)
#pragma unroll
        for (int ni = 0; ni < 2; ++ni)
          acc[mi][ni] =
              __builtin_amdgcn_mfma_f32_16x16x32_bf16(af[mi], bfr[ni], acc[mi][ni], 0, 0, 0);
      asm volatile("s_barrier" ::: "memory");
      bufc = (bufc + 1 == 3) ? 0 : bufc + 1;
    }
#undef VSTAGE
#pragma unroll
    for (int mi = 0; mi < 4; ++mi)
#pragma unroll
      for (int ni = 0; ni < 2; ++ni) {
        int s = n0 + wn + ni * 16 + lr;
        int sig = (s & ~31) | ((s & 15) << 1) | ((s >> 4) & 1);
#pragma unroll
        for (int r = 0; r < 4; ++r) {
          int d = m0 + wm + mi * 16 + lg * 4 + r;
          Vg[(size_t)d * SEQ + sig] = (bf16_t)(acc[mi][ni][r] + bias[VOFF + d]);
        }
      }
  }
}

// ---------- O-projection GEMM: 128x64 tiles, grid 512 = 2 blocks/CU ----------
__global__ __launch_bounds__(256) void k_ogemm(const bf16_t* __restrict__ A,
                                               const bf16_t* __restrict__ Bt,
                                               float* __restrict__ C) {
  __shared__ __align__(16) bf16_t As[3][128 * 32];
  __shared__ __align__(16) bf16_t Bs[3][64 * 32];
  const int tid = threadIdx.x;
  const int l = tid & 63, w = tid >> 6;
  const int lr = l & 15, lg = l >> 4;
  const int bid = blockIdx.x;
  const int swz = (bid & 7) * 64 + (bid >> 3);  // 512 = 8*64
  const int m0 = (swz >> 5) * 128, n0 = (swz & 31) * 64;
  const int wm = (w >> 1) * 64, wn = (w & 1) * 32;
  const int K = 2048, NT = 64;
  f32x4 acc[4][2] = {};

#define OSTAGE(buf, ktv)                                                         \
  {                                                                              \
    _Pragma("unroll") for (int t = 0; t < 2; ++t) {                              \
      int c = t * 256 + tid;                                                     \
      int r = c >> 2, ss = (c & 3) ^ ((r >> 1) & 3);                             \
      gl_lds16(A + (size_t)(m0 + r) * K + (ktv) + ss * 8,                        \
               &As[buf][(size_t)(t * 256 + w * 64) * 8]);                        \
    }                                                                            \
    {                                                                            \
      int c = tid;                                                               \
      int r = c >> 2, ss = (c & 3) ^ ((r >> 1) & 3);                             \
      gl_lds16(Bt + (size_t)(n0 + r) * K + (ktv) + ss * 8,                       \
               &Bs[buf][(size_t)(w * 64) * 8]);                                  \
    }                                                                            \
  }

  OSTAGE(0, 0);
  OSTAGE(1, 32);
  int bufc = 0;
  for (int i = 0; i < NT; ++i) {
    if (i + 2 < NT) {
      int bn = bufc + 2; if (bn >= 3) bn -= 3;
      OSTAGE(bn, (i + 2) * 32);
      asm volatile("s_waitcnt vmcnt(6)" ::: "memory");
    } else if (i + 2 == NT) {
      asm volatile("s_waitcnt vmcnt(3)" ::: "memory");
    } else {
      asm volatile("s_waitcnt vmcnt(0)" ::: "memory");
    }
    asm volatile("s_barrier" ::: "memory");
    bf16x8 af[4], bfr[2];
#pragma unroll
    for (int i4 = 0; i4 < 4; ++i4) {
      int ra = wm + i4 * 16 + lr;
      af[i4] = *(const bf16x8*)&As[bufc][ra * 32 + ((lg ^ ((ra >> 1) & 3)) * 8)];
    }
#pragma unroll
    for (int i4 = 0; i4 < 2; ++i4) {
      int rb = wn + i4 * 16 + lr;
      bfr[i4] = *(const bf16x8*)&Bs[bufc][rb * 32 + ((lg ^ ((rb >> 1) & 3)) * 8)];
    }
#pragma unroll
    for (int mi = 0; mi < 4; ++mi)
#pragma unroll
      for (int ni = 0; ni < 2; ++ni)
        acc[mi][ni] =
            __builtin_amdgcn_mfma_f32_16x16x32_bf16(af[mi], bfr[ni], acc[mi][ni], 0, 0, 0);
    asm volatile("s_barrier" ::: "memory");
    bufc = (bufc + 1 == 3) ? 0 : bufc + 1;
  }
#undef OSTAGE

#pragma unroll
  for (int mi = 0; mi < 4; ++mi)
#pragma unroll
    for (int ni = 0; ni < 2; ++ni) {
      int col = n0 + wn + ni * 16 + lr;
#pragma unroll
      for (int r = 0; r < 4; ++r) {
        int row = m0 + wm + mi * 16 + lg * 4 + r;
        C[(size_t)row * 2048 + col] = acc[mi][ni][r];
      }
    }
}

// ---------- flash attention — R13 kernel (54.0 us): counted-vmcnt dbuf,
// swapped QK^T, in-register P, defer-max THR=8, V-fragment hoist ----------
__global__ __launch_bounds__(256) void k_attn(const bf16_t* __restrict__ QKV,
                                              const bf16_t* __restrict__ Vg,
                                              bf16_t* __restrict__ AO) {
  __shared__ __align__(16) bf16_t Kl[2 * 64 * 128];
  __shared__ __align__(16) bf16_t Vl[2 * 64 * 128];
  const int h = blockIdx.x;
  const int y = blockIdx.y;
  const int qb = (y < 16) ? (31 - y) : (y - 16);  // pair heavy+light per CU (sum=33)
  const int hkv = h >> 3;
  const int tid = threadIdx.x;
  const int l = tid & 63, w = tid >> 6;
  const int lr = l & 15, lg = l >> 4;
  const int q0 = qb * 64 + w * 16;

  // Q fragments (B-operand: col=lane&15 -> q=lr ; dh-slot=(lane>>4)*8+e)
  bf16x8 qf[4];
#pragma unroll
  for (int dt = 0; dt < 4; ++dt)
    qf[dt] = *(const bf16x8*)(QKV + (size_t)(q0 + lr) * NQKV + h * HDIM + dt * 32 + lg * 8);

  f32x4 oa[8] = {};
  float m = -1e30f, ls = 0.0f;

  // staging source pointers (pre-swizzled global source, linear LDS dest)
  const bf16_t* srcK[4];
  const bf16_t* srcV[4];
#pragma unroll
  for (int t = 0; t < 4; ++t) {
    int c = t * 256 + tid;
    int r = c >> 4, ss = (c & 15) ^ (r & 15);
    srcK[t] = QKV + (size_t)r * NQKV + KOFF + hkv * HDIM + ss * 8;
    srcV[t] = Vg + (size_t)(hkv * HDIM + 2 * r + (ss >> 3)) * SEQ + (ss & 7) * 8;
  }

#define STAGE(b, kbv)                                                        \
  {                                                                          \
    bf16_t* Kb = Kl + (b) * 8192;                                            \
    bf16_t* Vb = Vl + (b) * 8192;                                            \
    _Pragma("unroll") for (int t = 0; t < 4; ++t)                            \
        gl_lds16(srcK[t] + (size_t)(kbv) * 64 * NQKV,                        \
                 Kb + (size_t)(t * 256 + w * 64) * 8);                       \
    _Pragma("unroll") for (int t = 0; t < 4; ++t)                            \
        gl_lds16(srcV[t] + (kbv) * 64, Vb + (size_t)(t * 256 + w * 64) * 8); \
  }

  // prologue: stage tiles 0 and 1 (tile 1 junk when qb==0 — in-bounds, unused)
  STAGE(0, 0);
  STAGE(1, 1);
  asm volatile("s_waitcnt vmcnt(8)" ::: "memory");
  asm volatile("s_barrier" ::: "memory");

  for (int kb = 0; kb <= qb; ++kb) {
    const bf16_t* Kb = Kl + (kb & 1) * 8192;
    const bf16_t* Vb = Vl + (kb & 1) * 8192;

    // S^T = K @ Q^T : lane holds S[k=ki*16+lg*4+r][q=lr]
    float sc[4][4];
#pragma unroll
    for (int ki = 0; ki < 4; ++ki) {
      f32x4 sa = {};
      int krow = ki * 16 + lr;
#pragma unroll
      for (int dt = 0; dt < 4; ++dt) {
        bf16x8 kf = *(const bf16x8*)(Kb + krow * 128 + (((dt * 4 + lg) ^ lr) * 8));
        sa = __builtin_amdgcn_mfma_f32_16x16x32_bf16(kf, qf[dt], sa, 0, 0, 0);
      }
#pragma unroll
      for (int r = 0; r < 4; ++r) {
        float s = sa[r] * SCALE;
        if (kb == qb) {
          int kg = kb * 64 + ki * 16 + lg * 4 + r;
          if (kg > q0 + lr) s = -1e30f;
        }
        sc[ki][r] = s;
      }
    }

    // V fragments hoisted: independent of QK^T results; ds_read latency hides
    // under the softmax VALU chain below.
    bf16x8 vf[2][8];
#pragma unroll
    for (int kp = 0; kp < 2; ++kp)
#pragma unroll
      for (int dt = 0; dt < 8; ++dt) {
        int R = dt * 8 + (lr >> 1);
        int slot = (((lr & 1) * 8 + kp * 4 + lg) ^ (R & 15));
        vf[kp][dt] = *(const bf16x8*)(Vb + R * 128 + slot * 8);
      }

    // online softmax for q=lr: in-lane tree over 16 + 2 shfl across lg groups
    float t0 = fmaxf(fmaxf(sc[0][0], sc[0][1]), fmaxf(sc[0][2], sc[0][3]));
    float t1 = fmaxf(fmaxf(sc[1][0], sc[1][1]), fmaxf(sc[1][2], sc[1][3]));
    float t2 = fmaxf(fmaxf(sc[2][0], sc[2][1]), fmaxf(sc[2][2], sc[2][3]));
    float t3 = fmaxf(fmaxf(sc[3][0], sc[3][1]), fmaxf(sc[3][2], sc[3][3]));
    float tm = fmaxf(fmaxf(t0, t1), fmaxf(t2, t3));
    tm = fmaxf(tm, __shfl_xor(tm, 16));
    tm = fmaxf(tm, __shfl_xor(tm, 32));

    // T13 defer-max: only rescale when some q-row's max grew beyond m+8.
    if (!__all(tm <= m + 8.0f)) {
      float mn = fmaxf(m, tm);
      float al = __expf(m - mn);
      m = mn;
      ls *= al;
      float a0 = __shfl(al, lg * 4 + 0);
      float a1 = __shfl(al, lg * 4 + 1);
      float a2 = __shfl(al, lg * 4 + 2);
      float a3 = __shfl(al, lg * 4 + 3);
#pragma unroll
      for (int dt = 0; dt < 8; ++dt) {
        oa[dt][0] *= a0; oa[dt][1] *= a1; oa[dt][2] *= a2; oa[dt][3] *= a3;
      }
    }

    float rs = 0.0f;
#pragma unroll
    for (int ki = 0; ki < 4; ++ki) {
      float p0 = __expf(sc[ki][0] - m), p1 = __expf(sc[ki][1] - m);
      float p2 = __expf(sc[ki][2] - m), p3 = __expf(sc[ki][3] - m);
      sc[ki][0] = p0; sc[ki][1] = p1; sc[ki][2] = p2; sc[ki][3] = p3;
      rs += (p0 + p1) + (p2 + p3);
    }
    rs += __shfl_xor(rs, 16);
    rs += __shfl_xor(rs, 32);
    ls += rs;

    // pack P into A-fragments: pf[kp][e] = sc[2kp+(e&1)][e>>1]
    bf16x8 pf[2];
#pragma unroll
    for (int kp = 0; kp < 2; ++kp) {
      pf[kp][0] = (bf16_t)sc[2 * kp][0]; pf[kp][1] = (bf16_t)sc[2 * kp + 1][0];
      pf[kp][2] = (bf16_t)sc[2 * kp][1]; pf[kp][3] = (bf16_t)sc[2 * kp + 1][1];
      pf[kp][4] = (bf16_t)sc[2 * kp][2]; pf[kp][5] = (bf16_t)sc[2 * kp + 1][2];
      pf[kp][6] = (bf16_t)sc[2 * kp][3]; pf[kp][7] = (bf16_t)sc[2 * kp + 1][3];
    }

    // O += P @ V  (C[q][d]: col=lane&15=d, row=lg*4+reg=q)
#pragma unroll
    for (int kp = 0; kp < 2; ++kp)
#pragma unroll
      for (int dt = 0; dt < 8; ++dt)
        oa[dt] = __builtin_amdgcn_mfma_f32_16x16x32_bf16(pf[kp], vf[kp][dt], oa[dt], 0, 0, 0);

    // pipeline turn: free buf[kb&1], refill with tile kb+2, wait tile kb+1
    asm volatile("s_barrier" ::: "memory");
    if (kb + 2 <= qb) {
      STAGE(kb & 1, kb + 2);
      asm volatile("s_waitcnt vmcnt(8)" ::: "memory");
      asm volatile("s_barrier" ::: "memory");
    } else if (kb + 1 <= qb) {
      asm volatile("s_waitcnt vmcnt(0)" ::: "memory");
      asm volatile("s_barrier" ::: "memory");
    }
  }
#undef STAGE
  asm volatile("s_waitcnt vmcnt(0)" ::: "memory");

  // epilogue: normalize and store; lane holds O[q=lg*4+r][d=dt*16+lr]
  float l0 = __shfl(ls, lg * 4 + 0);
  float l1 = __shfl(ls, lg * 4 + 1);
  float l2 = __shfl(ls, lg * 4 + 2);
  float l3 = __shfl(ls, lg * 4 + 3);
  float i0 = 1.0f / l0, i1 = 1.0f / l1, i2 = 1.0f / l2, i3 = 1.0f / l3;
#pragma unroll
  for (int dt = 0; dt < 8; ++dt) {
    int d = h * HDIM + dt * 16 + lr;
    AO[(size_t)(q0 + lg * 4 + 0) * HID + d] = (bf16_t)(oa[dt][0] * i0);
    AO[(size_t)(q0 + lg * 4 + 1) * HID + d] = (bf16_t)(oa[dt][1] * i1);
    AO[(size_t)(q0 + lg * 4 + 2) * HID + d] = (bf16_t)(oa[dt][2] * i2);
    AO[(size_t)(q0 + lg * 4 + 3) * HID + d] = (bf16_t)(oa[dt][3] * i3);
  }
}

extern "C" void kernel_launch(void* const* d_in, const int* in_sizes, int n_in,
                              void* d_out, int out_size, void* d_ws, size_t ws_size,
                              hipStream_t stream) {
  (void)in_sizes; (void)n_in; (void)out_size; (void)ws_size;
  const float* x  = (const float*)d_in[0];
  const float* Wq = (const float*)d_in[1];
  const float* bq = (const float*)d_in[2];
  const float* Wk = (const float*)d_in[3];
  const float* bk = (const float*)d_in[4];
  const float* Wv = (const float*)d_in[5];
  const float* bv = (const float*)d_in[6];
  const float* Wo = (const float*)d_in[7];
  float* outp = (float*)d_out;

  char* ws = (char*)d_ws;
  const size_t OFF_XB   = 0;                      // [2048][2048] bf16
  const size_t OFF_WQKV = 8388608;                // [2560][2048] bf16 (Wq^T;Wk^T;Wv^T)
  const size_t OFF_WOT  = OFF_WQKV + 10485760;    // [2048][2048] bf16
  const size_t OFF_QKV  = OFF_WOT + 8388608;      // [2048][2560] bf16 (V cols unused)
  const size_t OFF_VT   = OFF_QKV + 10485760;     // [256][2048] bf16 (sigma-interleaved)
  const size_t OFF_AO   = OFF_VT + 1048576;       // [2048][2048] bf16
  const size_t OFF_BIAS = OFF_AO + 8388608;       // [2560] fp32
  bf16_t* xb    = (bf16_t*)(ws + OFF_XB);
  bf16_t* WqkvT = (bf16_t*)(ws + OFF_WQKV);
  bf16_t* WoT   = (bf16_t*)(ws + OFF_WOT);
  bf16_t* QKV   = (bf16_t*)(ws + OFF_QKV);
  bf16_t* Vg    = (bf16_t*)(ws + OFF_VT);
  bf16_t* AO    = (bf16_t*)(ws + OFF_AO);
  float*  bias  = (float*)(ws + OFF_BIAS);

  k_prep<<<3338, 256, 0, stream>>>(x, Wq, Wk, Wv, bq, bk, bv, xb, WqkvT, bias);
  k_proj<<<1376, 256, 0, stream>>>(xb, WqkvT, bias, Wo, WoT, QKV, Vg);
  k_attn<<<dim3(16, 32), 256, 0, stream>>>(QKV, Vg, AO);
  k_ogemm<<<512, 256, 0, stream>>>(AO, WoT, outp);
}